// Round 5
// baseline (146.094 us; speedup 1.0000x reference)
//
#include <hip/hip_runtime.h>

#define BB 2
#define NN 768
#define FF 128
#define HH 128
#define TS 32
#define NT (NN / TS)                 // 24 tiles per dim
#define NPAIR (NT * (NT + 1) / 2)    // 300 upper-triangular tile pairs
#define EROWS 2
#define THR 4e-3f

#define PIf   3.14159265358979323846f
#define PI2f  1.57079632679489661923f
#define TPIf  6.28318530717958647692f

// ---- exact f64 slow path: recompute gram from global Xc + f64 MLP --------
// Same values/fma order as the original always-f64 kernel; executed only in a
// cold branch (|m32| < THR, ~1e-4..1e-3 of edges).
__device__ __forceinline__
double edge_exact_f64(const double* __restrict__ Xc, const double* __restrict__ wpack,
                      int b, int i, int j, double init) {
    const double* xi0 = Xc + ((size_t)(b * 2 + 0) * NN + i) * 64;
    const double* xj0 = Xc + ((size_t)(b * 2 + 0) * NN + j) * 64;
    const double* xi1 = Xc + ((size_t)(b * 2 + 1) * NN + i) * 64;
    const double* xj1 = Xc + ((size_t)(b * 2 + 1) * NN + j) * 64;
    double p0 = 0.0, p1 = 0.0;
#pragma unroll 4
    for (int d2 = 0; d2 < 32; ++d2) {
        double2 a0 = *(const double2*)&xi0[2 * d2];
        double2 b0 = *(const double2*)&xj0[2 * d2];
        double2 a1 = *(const double2*)&xi1[2 * d2];
        double2 b1 = *(const double2*)&xj1[2 * d2];
        p0 = fma(a0.y, b0.y, fma(a0.x, b0.x, p0));
        p1 = fma(a1.y, b1.y, fma(a1.x, b1.x, p1));
    }
    double m = init;
#pragma unroll 8
    for (int c = 0; c < HH; ++c) {
        double2 wab = *(const double2*)&wpack[4 * c];        // a, b
        double2 wbw = *(const double2*)&wpack[4 * c + 2];    // beta, wd
        double tt = fma(p1, wab.y, fma(p0, wab.x, wbw.x));
        tt = fmax(tt, 0.0);
        m = fma(tt, wbw.y, m);
    }
    return m;
}

// k1: feats = relu(X@w1+b1)@w2+b2 (f64 accum); Xc (f64) and Xcf (f32) written.
// Block 0 additionally builds the score-MLP angular LUT:
//   zero-bias => f(p0,p1) = sum_c wd_c*relu(a_c p0 + b_c p1) is homogeneous:
//   f = A_k p0 + B_k p1 in angular sector k. 256 breakpoints (bitonic-sorted),
//   per-sector (A,B) via active-set at the sector midpoint (continuity makes
//   all boundary/precision errors vanish near breaklines).
__global__ __launch_bounds__(128)
void edgefeat_kernel(const float* __restrict__ X,
                     const float* __restrict__ w1, const float* __restrict__ b1,
                     const float* __restrict__ w2, const float* __restrict__ b2,
                     const float* __restrict__ gatep,
                     const float* __restrict__ sm_w1, const float* __restrict__ sm_b1,
                     const float* __restrict__ sm_w2,
                     double* __restrict__ Xc, float* __restrict__ Xcf,
                     double* __restrict__ wpack, float4* __restrict__ wpackf,
                     float2* __restrict__ ABg, float* __restrict__ bpg,
                     unsigned* __restrict__ bsg, unsigned* __restrict__ flg) {
    __shared__ float  Xs[EROWS][FF];
    __shared__ double Hs[EROWS][HH];
    __shared__ float  sbp[256];
    __shared__ float  sWa[128], sWb[128], sWw[128];
    __shared__ int    snz;
    const int h = threadIdx.x;            // 0..127
    const int row0 = blockIdx.x * EROWS;  // global row in [0, B*N)
    for (int r = 0; r < EROWS; ++r) Xs[r][h] = X[(size_t)(row0 + r) * FF + h];

    if (blockIdx.x == 0) {
        if (h == 0) snz = 0;
        double a  = (double)sm_w1[h];
        double bq = (double)sm_w1[HH + h];
        double be = (double)sm_b1[h];
        double wd = (double)sm_w2[2 * h + 1] - (double)sm_w2[2 * h + 0];
        wpack[4 * h + 0] = a;  wpack[4 * h + 1] = bq;
        wpack[4 * h + 2] = be; wpack[4 * h + 3] = wd;
        wpackf[h] = make_float4((float)a, (float)bq, (float)be, (float)wd);
        sWa[h] = (float)a; sWb[h] = (float)bq; sWw[h] = (float)wd;
        __syncthreads();          // snz init visible
        if (be != 0.0) atomicOr(&snz, 1);
        // breakpoints: angles where a*cos + b*sin = 0
        float phi = (float)atan2(bq, a);
        float t1 = phi + PI2f; if (t1 >= PIf) t1 -= TPIf;
        float t2 = phi - PI2f; if (t2 < -PIf) t2 += TPIf;
        sbp[h] = t1; sbp[h + 128] = t2;
        // bitonic sort 256 elems, 128 threads
        for (int k = 2; k <= 256; k <<= 1) {
            for (int j = k >> 1; j > 0; j >>= 1) {
                __syncthreads();
                int i  = ((h & ~(j - 1)) << 1) | (h & (j - 1));
                int ix = i | j;
                float x = sbp[i], y = sbp[ix];
                bool up = ((i & k) == 0);
                if ((x > y) == up) { sbp[i] = y; sbp[ix] = x; }
            }
        }
        __syncthreads();
        bpg[h] = sbp[h]; bpg[h + 128] = sbp[h + 128];
        // binstart[bin] = #bp < left edge of bin (257 entries)
        for (int bin = h; bin <= 256; bin += 128) {
            float left = -PIf + (float)bin * (PIf / 128.0f);
            int cnt = 0;
            for (int i2 = 0; i2 < 256; ++i2) cnt += (sbp[i2] < left) ? 1 : 0;
            bsg[bin] = (unsigned)cnt;
        }
        // per-sector (A,B) via active set at sector midpoint
        for (int sec = h; sec < 256; sec += 128) {
            float lo = sbp[sec];
            float hi = (sec < 255) ? sbp[sec + 1] : sbp[0] + TPIf;
            float thm = 0.5f * (lo + hi), sn, cs;
            __sincosf(thm, &sn, &cs);
            float A = 0.f, B = 0.f;
            for (int c2 = 0; c2 < 128; ++c2) {
                float hv = fmaf(sWa[c2], cs, sWb[c2] * sn);
                if (hv > 0.f) { A = fmaf(sWw[c2], sWa[c2], A); B = fmaf(sWw[c2], sWb[c2], B); }
            }
            ABg[sec] = make_float2(A, B);
        }
        __syncthreads();
        if (h == 0) flg[0] = (unsigned)snz;
    }
    __syncthreads();

    double acc[EROWS];
    double bb = (double)b1[h];
    for (int r = 0; r < EROWS; ++r) acc[r] = bb;
    for (int f = 0; f < FF; ++f) {
        double w = (double)w1[f * HH + h];        // coalesced across h
        for (int r = 0; r < EROWS; ++r) acc[r] = fma((double)Xs[r][f], w, acc[r]);
    }
    for (int r = 0; r < EROWS; ++r) Hs[r][h] = acc[r] > 0.0 ? acc[r] : 0.0;
    __syncthreads();
    bb = (double)b2[h];
    for (int r = 0; r < EROWS; ++r) acc[r] = bb;
    for (int c = 0; c < HH; ++c) {
        double w = (double)w2[c * HH + h];
        for (int r = 0; r < EROWS; ++r) acc[r] = fma(Hs[r][c], w, acc[r]);
    }
    const double gate = (double)gatep[0];
    const int k = h & 1, d = h >> 1;
    const int b = row0 / NN;
    const int i0 = row0 % NN;
    for (int r = 0; r < EROWS; ++r) {
        double v = (double)Xs[r][h] + gate * acc[r];
        size_t idx = (((size_t)(b * 2 + k)) * NN + (i0 + r)) * 64 + d;
        Xc[idx]  = v;
        Xcf[idx] = (float)v;
    }
}

// angular-LUT margin eval: f = A_sec*p0 + B_sec*p1 (zero-bias fast path)
__device__ __forceinline__
float lut_eval(float p0, float p1, const float* __restrict__ bpl,
               const unsigned* __restrict__ bsl, const float2* __restrict__ ABl) {
    float th = atan2f(p1, p0);
    int bin = (int)((th + PIf) * (128.0f / PIf));
    bin = bin < 0 ? 0 : (bin > 255 ? 255 : bin);
    int idx = (int)bsl[bin];
    while (idx < 256 && bpl[idx] <= th) ++idx;   // expected ~1-2 iters
    int sec = (idx == 0) ? 255 : idx - 1;
    float2 ab = ABl[sec];
    return fmaf(ab.x, p0, ab.y * p1);
}

// k2: 512 threads per 32x32 tile; lane-pair K-slicing for the gram (shfl reduce),
// then per-edge margin via angular LUT (or full MLP loop if biases nonzero),
// rare exact-f64 re-decide, symmetric write.
__global__ __launch_bounds__(512, 6)
void edge_decide_kernel(const double* __restrict__ Xc,
                        const float* __restrict__ Xcf,
                        const double* __restrict__ wpack,
                        const float4* __restrict__ wpackf,
                        const float2* __restrict__ ABg, const float* __restrict__ bpg,
                        const unsigned* __restrict__ bsg, const unsigned* __restrict__ flg,
                        const float* __restrict__ sm_b2,
                        const float* __restrict__ gumbel,
                        float* __restrict__ out) {
    __shared__ float  Ai[2][TS][66];   // stride 66: 2-way bank alias only (free)
    __shared__ float  Aj[2][TS][66];
    __shared__ float  As[TS][TS + 1];
    __shared__ float4 Wl[HH];
    __shared__ float  bpl[256];
    __shared__ float2 ABl[256];
    __shared__ unsigned bsl[256];
    const int b = blockIdx.y;
    const int t = blockIdx.x;
    // decode upper-triangular pair index: t -> (ti, tj), tj >= ti   (T=24)
    int ti = (int)((49.0 - sqrt(2401.0 - 8.0 * (double)t)) * 0.5);
    int base = ti * (49 - ti) / 2;
    if (t < base) { --ti; base = ti * (49 - ti) / 2; }
    else { int nb = (ti + 1) * (48 - ti) / 2; if (t >= nb) { ++ti; base = nb; } }
    const int tj = t - base + ti;
    const int tid = threadIdx.x;
    const int i0 = ti * TS, j0 = tj * TS;

    // stage f32 Xcf tiles + LUT tables
    for (int q = 0; q < 4; ++q) {
        int flat = tid + 512 * q;
        int dp = flat & 31;
        int r  = (flat >> 5) & 31;
        int k  = flat >> 10;
        size_t rowbase = ((size_t)(b * 2 + k)) * NN;
        *(float2*)&Ai[k][r][2 * dp] = *(const float2*)&Xcf[(rowbase + i0 + r) * 64 + 2 * dp];
        *(float2*)&Aj[k][r][2 * dp] = *(const float2*)&Xcf[(rowbase + j0 + r) * 64 + 2 * dp];
    }
    if (tid < 256) { bpl[tid] = bpg[tid]; ABl[tid] = ABg[tid]; bsl[tid] = bsg[tid]; }
    if (tid < HH)  Wl[tid] = wpackf[tid];
    const unsigned biased = flg[0];

    const int s  = tid & 1;          // slice within lane pair
    const int e  = tid >> 1;         // edge-quad id 0..255
    const int rh = e >> 4;           // 0..15
    const int ch = e & 15;           // 0..15
    const int r0 = rh, r1 = rh + 16;
    const int c0 = 2 * ch, c1 = c0 + 1;
    const int gi0 = i0 + r0, gi1 = i0 + r1;
    const int gj0 = j0 + c0, gj1 = j0 + c1;

    // gumbel loads early (both lanes of the pair; same addresses coalesce)
    float4 g0v = *(const float4*)&gumbel[(((size_t)b * NN + gi0) * NN + gj0) * 2];
    float4 g1v = *(const float4*)&gumbel[(((size_t)b * NN + gi1) * NN + gj0) * 2];
    __syncthreads();

    // f32 gram, K-sliced: slice s covers d2 = s + 2*it
    float p000 = 0.f, p001 = 0.f, p010 = 0.f, p011 = 0.f;
    float p100 = 0.f, p101 = 0.f, p110 = 0.f, p111 = 0.f;
#pragma unroll
    for (int it = 0; it < 16; ++it) {
        const int d2 = s + 2 * it;
        float2 a00 = *(const float2*)&Ai[0][r0][2 * d2];
        float2 a01 = *(const float2*)&Ai[0][r1][2 * d2];
        float2 a10 = *(const float2*)&Ai[1][r0][2 * d2];
        float2 a11 = *(const float2*)&Ai[1][r1][2 * d2];
        float2 b00 = *(const float2*)&Aj[0][c0][2 * d2];
        float2 b01 = *(const float2*)&Aj[0][c1][2 * d2];
        float2 b10 = *(const float2*)&Aj[1][c0][2 * d2];
        float2 b11 = *(const float2*)&Aj[1][c1][2 * d2];
        p000 = fmaf(a00.y, b00.y, fmaf(a00.x, b00.x, p000));
        p001 = fmaf(a00.y, b01.y, fmaf(a00.x, b01.x, p001));
        p010 = fmaf(a01.y, b00.y, fmaf(a01.x, b00.x, p010));
        p011 = fmaf(a01.y, b01.y, fmaf(a01.x, b01.x, p011));
        p100 = fmaf(a10.y, b10.y, fmaf(a10.x, b10.x, p100));
        p101 = fmaf(a10.y, b11.y, fmaf(a10.x, b11.x, p101));
        p110 = fmaf(a11.y, b10.y, fmaf(a11.x, b10.x, p110));
        p111 = fmaf(a11.y, b11.y, fmaf(a11.x, b11.x, p111));
    }
    // butterfly-reduce p over the lane pair; both lanes get full dots
    p000 += __shfl_xor(p000, 1); p001 += __shfl_xor(p001, 1);
    p010 += __shfl_xor(p010, 1); p011 += __shfl_xor(p011, 1);
    p100 += __shfl_xor(p100, 1); p101 += __shfl_xor(p101, 1);
    p110 += __shfl_xor(p110, 1); p111 += __shfl_xor(p111, 1);

    // margin init (f64 kept exact for the fallback)
    const double bd = (double)sm_b2[1] - (double)sm_b2[0];
    double i00 = bd + ((double)g0v.y - (double)g0v.x);
    double i01 = bd + ((double)g0v.w - (double)g0v.z);
    double i10 = bd + ((double)g1v.y - (double)g1v.x);
    double i11 = bd + ((double)g1v.w - (double)g1v.z);

    float m00, m01, m10, m11;
    if (!biased) {
        // lane s evaluates 2 of the 4 edges via the angular LUT; exchange by shfl
        float pa0 = (s == 0) ? p000 : p010, pa1 = (s == 0) ? p100 : p110;
        float pb0 = (s == 0) ? p001 : p011, pb1 = (s == 0) ? p101 : p111;
        float ia  = (s == 0) ? (float)i00 : (float)i10;
        float ib  = (s == 0) ? (float)i01 : (float)i11;
        float ma = lut_eval(pa0, pa1, bpl, bsl, ABl) + ia;
        float mb = lut_eval(pb0, pb1, bpl, bsl, ABl) + ib;
        float moa = __shfl_xor(ma, 1);
        float mob = __shfl_xor(mb, 1);
        m00 = (s == 0) ? ma : moa;  m01 = (s == 0) ? mb : mob;
        m10 = (s == 0) ? moa : ma;  m11 = (s == 0) ? mob : mb;
    } else {
        // general path: full f32 MLP loop (weights broadcast from LDS)
        m00 = (float)i00; m01 = (float)i01; m10 = (float)i10; m11 = (float)i11;
#pragma unroll 8
        for (int c = 0; c < HH; ++c) {
            float4 w = Wl[c];
            float tt;
            tt = fmaf(p100, w.y, fmaf(p000, w.x, w.z)); tt = fmaxf(tt, 0.f); m00 = fmaf(tt, w.w, m00);
            tt = fmaf(p101, w.y, fmaf(p001, w.x, w.z)); tt = fmaxf(tt, 0.f); m01 = fmaf(tt, w.w, m01);
            tt = fmaf(p110, w.y, fmaf(p010, w.x, w.z)); tt = fmaxf(tt, 0.f); m10 = fmaf(tt, w.w, m10);
            tt = fmaf(p111, w.y, fmaf(p011, w.x, w.z)); tt = fmaxf(tt, 0.f); m11 = fmaf(tt, w.w, m11);
        }
    }

    if (s == 0) {
        float A00 = m00 > 0.f ? 1.f : 0.f;
        float A01 = m01 > 0.f ? 1.f : 0.f;
        float A10 = m10 > 0.f ? 1.f : 0.f;
        float A11 = m11 > 0.f ? 1.f : 0.f;
        float fm = fminf(fminf(fabsf(m00), fabsf(m01)), fminf(fabsf(m10), fabsf(m11)));
        if (__builtin_expect(fm < THR, 0)) {
            // rare: exact f64 re-decide (bit-identical to original f64 kernel)
            if (fabsf(m00) < THR) A00 = edge_exact_f64(Xc, wpack, b, gi0, gj0, i00) > 0.0 ? 1.f : 0.f;
            if (fabsf(m01) < THR) A01 = edge_exact_f64(Xc, wpack, b, gi0, gj1, i01) > 0.0 ? 1.f : 0.f;
            if (fabsf(m10) < THR) A10 = edge_exact_f64(Xc, wpack, b, gi1, gj0, i10) > 0.0 ? 1.f : 0.f;
            if (fabsf(m11) < THR) A11 = edge_exact_f64(Xc, wpack, b, gi1, gj1, i11) > 0.0 ? 1.f : 0.f;
        }
        As[r0][c0] = A00; As[r0][c1] = A01;
        As[r1][c0] = A10; As[r1][c1] = A11;
    }
    __syncthreads();

    if (s == 0) {
        float A00 = As[r0][c0], A01 = As[r0][c1];
        float A10 = As[r1][c0], A11 = As[r1][c1];
        if (ti != tj) {
            *(float2*)&out[((size_t)b * NN + gi0) * NN + gj0] = make_float2(A00, A01);
            *(float2*)&out[((size_t)b * NN + gi1) * NN + gj0] = make_float2(A10, A11);
            float2 t0 = make_float2(As[c0][r0], As[c1][r0]);
            *(float2*)&out[((size_t)b * NN + j0 + r0) * NN + i0 + c0] = t0;
            float2 t1 = make_float2(As[c0][r1], As[c1][r1]);
            *(float2*)&out[((size_t)b * NN + j0 + r1) * NN + i0 + c0] = t1;
        } else {
            float v00 = (r0 < c0) ? A00 : ((r0 > c0) ? As[c0][r0] : 0.0f);
            float v01 = (r0 < c1) ? A01 : ((r0 > c1) ? As[c1][r0] : 0.0f);
            float v10 = (r1 < c0) ? A10 : ((r1 > c0) ? As[c0][r1] : 0.0f);
            float v11 = (r1 < c1) ? A11 : ((r1 > c1) ? As[c1][r1] : 0.0f);
            *(float2*)&out[((size_t)b * NN + gi0) * NN + gj0] = make_float2(v00, v01);
            *(float2*)&out[((size_t)b * NN + gi1) * NN + gj0] = make_float2(v10, v11);
        }
    }
}

extern "C" void kernel_launch(void* const* d_in, const int* in_sizes, int n_in,
                              void* d_out, int out_size, void* d_ws, size_t ws_size,
                              hipStream_t stream) {
    const float* X      = (const float*)d_in[0];
    const float* ef_w1  = (const float*)d_in[1];
    const float* ef_b1  = (const float*)d_in[2];
    const float* ef_w2  = (const float*)d_in[3];
    const float* ef_b2  = (const float*)d_in[4];
    const float* gate   = (const float*)d_in[5];
    const float* sm_w1  = (const float*)d_in[6];
    const float* sm_b1  = (const float*)d_in[7];
    const float* sm_w2  = (const float*)d_in[8];
    const float* sm_b2  = (const float*)d_in[9];
    const float* gumbel = (const float*)d_in[10];
    float* out = (float*)d_out;

    double*   Xc     = (double*)d_ws;                      // 2*2*768*64 doubles = 1.5 MiB
    double*   wpack  = Xc + (size_t)BB * 2 * NN * 64;      // 512 doubles
    float4*   wpackf = (float4*)(wpack + 4 * HH);          // 128 float4   (2048 B)
    float2*   ABg    = (float2*)(wpackf + HH);             // 256 float2   (2048 B)
    float*    bpg    = (float*)(ABg + 256);                // 256 f32      (1024 B)
    unsigned* bsg    = (unsigned*)(bpg + 256);             // 260 u32      (1040 B)
    unsigned* flg    = bsg + 260;                          // 4 u32        (16 B)
    float*    Xcf    = (float*)(flg + 4);                  // 768 KiB f32 copy

    edgefeat_kernel<<<BB * NN / EROWS, 128, 0, stream>>>(
        X, ef_w1, ef_b1, ef_w2, ef_b2, gate, sm_w1, sm_b1, sm_w2,
        Xc, Xcf, wpack, wpackf, ABg, bpg, bsg, flg);
    dim3 grid(NPAIR, BB);
    edge_decide_kernel<<<grid, 512, 0, stream>>>(
        Xc, Xcf, wpack, wpackf, ABg, bpg, bsg, flg, sm_b2, gumbel, out);
}

// Round 6
// 119.143 us; speedup vs baseline: 1.2262x; 1.2262x over previous
//
#include <hip/hip_runtime.h>

#define BB 2
#define NN 768
#define FF 128
#define HH 128
#define TS 32
#define LST 68                       // LDS row stride (floats): 272B rows, 16B-aligned, <=2-way banks
#define NT (NN / TS)                 // 24 tiles per dim
#define NPAIR (NT * (NT + 1) / 2)    // 300 upper-triangular tile pairs
#define EROWS 2
#define THR 4e-3f

// ---- exact f64 slow path: recompute gram from global Xc + f64 MLP --------
// Same values/fma order as the original always-f64 kernel; executed only in a
// cold branch (|m32| < THR, ~1e-4 of edges). Fully inlined: no call ABI/spills.
__device__ __forceinline__
double edge_exact_f64(const double* __restrict__ Xc, const double* __restrict__ wpack,
                      int b, int i, int j, double init) {
    const double* xi0 = Xc + ((size_t)(b * 2 + 0) * NN + i) * 64;
    const double* xj0 = Xc + ((size_t)(b * 2 + 0) * NN + j) * 64;
    const double* xi1 = Xc + ((size_t)(b * 2 + 1) * NN + i) * 64;
    const double* xj1 = Xc + ((size_t)(b * 2 + 1) * NN + j) * 64;
    double p0 = 0.0, p1 = 0.0;
#pragma unroll 4
    for (int d2 = 0; d2 < 32; ++d2) {
        double2 a0 = *(const double2*)&xi0[2 * d2];
        double2 b0 = *(const double2*)&xj0[2 * d2];
        double2 a1 = *(const double2*)&xi1[2 * d2];
        double2 b1 = *(const double2*)&xj1[2 * d2];
        p0 = fma(a0.y, b0.y, fma(a0.x, b0.x, p0));
        p1 = fma(a1.y, b1.y, fma(a1.x, b1.x, p1));
    }
    double m = init;
#pragma unroll 8
    for (int c = 0; c < HH; ++c) {
        double2 wab = *(const double2*)&wpack[4 * c];        // a, b
        double2 wbw = *(const double2*)&wpack[4 * c + 2];    // beta, wd
        double tt = fma(p1, wab.y, fma(p0, wab.x, wbw.x));
        tt = fmax(tt, 0.0);
        m = fma(tt, wbw.y, m);
    }
    return m;
}

// k1: feats = relu(X@w1+b1)@w2+b2 (f64 accum); Xc (f64) and Xcf (f32) both written.
// block 0 additionally packs the score-MLP weights (f64 + f32).
__global__ __launch_bounds__(128)
void edgefeat_kernel(const float* __restrict__ X,
                     const float* __restrict__ w1, const float* __restrict__ b1,
                     const float* __restrict__ w2, const float* __restrict__ b2,
                     const float* __restrict__ gatep,
                     const float* __restrict__ sm_w1, const float* __restrict__ sm_b1,
                     const float* __restrict__ sm_w2,
                     double* __restrict__ Xc, float* __restrict__ Xcf,
                     double* __restrict__ wpack, float4* __restrict__ wpackf) {
    __shared__ float  Xs[EROWS][FF];
    __shared__ double Hs[EROWS][HH];
    const int h = threadIdx.x;            // 0..127 output column
    const int row0 = blockIdx.x * EROWS;  // global row in [0, B*N)
    for (int r = 0; r < EROWS; ++r) Xs[r][h] = X[(size_t)(row0 + r) * FF + h];
    if (blockIdx.x == 0) {
        // wpack[c] = {w1[0,c], w1[1,c], b1[c], w2[c,1]-w2[c,0]}
        double a  = (double)sm_w1[h];
        double bq = (double)sm_w1[HH + h];
        double be = (double)sm_b1[h];
        double wd = (double)sm_w2[2 * h + 1] - (double)sm_w2[2 * h + 0];
        wpack[4 * h + 0] = a;  wpack[4 * h + 1] = bq;
        wpack[4 * h + 2] = be; wpack[4 * h + 3] = wd;
        wpackf[h] = make_float4((float)a, (float)bq, (float)be, (float)wd);
    }
    __syncthreads();
    double acc[EROWS];
    double bb = (double)b1[h];
    for (int r = 0; r < EROWS; ++r) acc[r] = bb;
    for (int f = 0; f < FF; ++f) {
        double w = (double)w1[f * HH + h];        // coalesced across h
        for (int r = 0; r < EROWS; ++r) acc[r] = fma((double)Xs[r][f], w, acc[r]);
    }
    for (int r = 0; r < EROWS; ++r) Hs[r][h] = acc[r] > 0.0 ? acc[r] : 0.0;
    __syncthreads();
    bb = (double)b2[h];
    for (int r = 0; r < EROWS; ++r) acc[r] = bb;
    for (int c = 0; c < HH; ++c) {
        double w = (double)w2[c * HH + h];
        for (int r = 0; r < EROWS; ++r) acc[r] = fma(Hs[r][c], w, acc[r]);
    }
    const double gate = (double)gatep[0];
    const int k = h & 1, d = h >> 1;
    const int b = row0 / NN;
    const int i0 = row0 % NN;
    for (int r = 0; r < EROWS; ++r) {
        double v = (double)Xs[r][h] + gate * acc[r];
        size_t idx = (((size_t)(b * 2 + k)) * NN + (i0 + r)) * 64 + d;
        Xc[idx]  = v;
        Xcf[idx] = (float)v;
    }
}

// k2: 512 threads per 32x32 tile. Lane-pair slicing (s = tid&1): each thread does
// half the gram K-dim (via b128 LDS reads) and half the MLP channels;
// __shfl_xor(1) butterflies reduce. Weights broadcast from LDS.
__global__ __launch_bounds__(512, 6)
void edge_decide_kernel(const double* __restrict__ Xc,
                        const float* __restrict__ Xcf,
                        const double* __restrict__ wpack,
                        const float4* __restrict__ wpackf,
                        const float* __restrict__ sm_b2,
                        const float* __restrict__ gumbel,
                        float* __restrict__ out) {
    __shared__ float  Ai[2][TS][LST];  // 272B rows: 16B-aligned, banks <=2-way (free)
    __shared__ float  Aj[2][TS][LST];
    __shared__ float4 Wl[HH];          // packed score-MLP weights {a,b,beta,wd}
    __shared__ float  As[TS][TS + 1];
    const int b = blockIdx.y;
    const int t = blockIdx.x;
    // decode upper-triangular pair index: t -> (ti, tj), tj >= ti   (T=24)
    int ti = (int)((49.0 - sqrt(2401.0 - 8.0 * (double)t)) * 0.5);
    int base = ti * (49 - ti) / 2;
    if (t < base) { --ti; base = ti * (49 - ti) / 2; }
    else { int nb = (ti + 1) * (48 - ti) / 2; if (t >= nb) { ++ti; base = nb; } }
    const int tj = t - base + ti;
    const int tid = threadIdx.x;
    const int i0 = ti * TS, j0 = tj * TS;

    // stage f32 Xcf tiles (coalesced float2 global reads)
    for (int q = 0; q < 4; ++q) {
        int flat = tid + 512 * q;        // pair index over (k, r, d2)
        int dp = flat & 31;
        int r  = (flat >> 5) & 31;
        int k  = flat >> 10;
        size_t rowbase = ((size_t)(b * 2 + k)) * NN;
        *(float2*)&Ai[k][r][2 * dp] = *(const float2*)&Xcf[(rowbase + i0 + r) * 64 + 2 * dp];
        *(float2*)&Aj[k][r][2 * dp] = *(const float2*)&Xcf[(rowbase + j0 + r) * 64 + 2 * dp];
    }
    if (tid < HH) Wl[tid] = wpackf[tid];

    const int s  = tid & 1;          // slice within lane pair
    const int e  = tid >> 1;         // edge-quad id 0..255
    const int rh = e >> 4;           // 0..15
    const int ch = e & 15;           // 0..15
    const int r0 = rh, r1 = rh + 16;
    const int c0 = 2 * ch, c1 = c0 + 1;
    const int gi0 = i0 + r0, gi1 = i0 + r1;
    const int gj0 = j0 + c0, gj1 = j0 + c1;

    // issue gumbel loads early (s==0 lanes only; hide global latency under gram)
    float4 g0v = make_float4(0.f, 0.f, 0.f, 0.f);
    float4 g1v = make_float4(0.f, 0.f, 0.f, 0.f);
    if (s == 0) {
        g0v = *(const float4*)&gumbel[(((size_t)b * NN + gi0) * NN + gj0) * 2];
        g1v = *(const float4*)&gumbel[(((size_t)b * NN + gi1) * NN + gj0) * 2];
    }
    __syncthreads();

    // f32 gram, K-sliced via b128 reads: slice s covers float4 index d4 = s + 2*it
    // (64 ds_read_b128 per thread vs 128 ds_read_b64 — half the LDS instr count
    // and half the wait-groups in the longest dependency phase)
    float p000 = 0.f, p001 = 0.f, p010 = 0.f, p011 = 0.f;
    float p100 = 0.f, p101 = 0.f, p110 = 0.f, p111 = 0.f;
#pragma unroll
    for (int it = 0; it < 8; ++it) {
        const int d4 = (s + 2 * it) * 4;    // float offset of the float4
        float4 a00 = *(const float4*)&Ai[0][r0][d4];
        float4 a01 = *(const float4*)&Ai[0][r1][d4];
        float4 a10 = *(const float4*)&Ai[1][r0][d4];
        float4 a11 = *(const float4*)&Ai[1][r1][d4];
        float4 b00 = *(const float4*)&Aj[0][c0][d4];
        float4 b01 = *(const float4*)&Aj[0][c1][d4];
        float4 b10 = *(const float4*)&Aj[1][c0][d4];
        float4 b11 = *(const float4*)&Aj[1][c1][d4];
        p000 = fmaf(a00.w, b00.w, fmaf(a00.z, b00.z, fmaf(a00.y, b00.y, fmaf(a00.x, b00.x, p000))));
        p001 = fmaf(a00.w, b01.w, fmaf(a00.z, b01.z, fmaf(a00.y, b01.y, fmaf(a00.x, b01.x, p001))));
        p010 = fmaf(a01.w, b00.w, fmaf(a01.z, b00.z, fmaf(a01.y, b00.y, fmaf(a01.x, b00.x, p010))));
        p011 = fmaf(a01.w, b01.w, fmaf(a01.z, b01.z, fmaf(a01.y, b01.y, fmaf(a01.x, b01.x, p011))));
        p100 = fmaf(a10.w, b10.w, fmaf(a10.z, b10.z, fmaf(a10.y, b10.y, fmaf(a10.x, b10.x, p100))));
        p101 = fmaf(a10.w, b11.w, fmaf(a10.z, b11.z, fmaf(a10.y, b11.y, fmaf(a10.x, b11.x, p101))));
        p110 = fmaf(a11.w, b10.w, fmaf(a11.z, b10.z, fmaf(a11.y, b10.y, fmaf(a11.x, b10.x, p110))));
        p111 = fmaf(a11.w, b11.w, fmaf(a11.z, b11.z, fmaf(a11.y, b11.y, fmaf(a11.x, b11.x, p111))));
    }
    // butterfly-reduce p over the lane pair; both lanes get the full dot
    p000 += __shfl_xor(p000, 1); p001 += __shfl_xor(p001, 1);
    p010 += __shfl_xor(p010, 1); p011 += __shfl_xor(p011, 1);
    p100 += __shfl_xor(p100, 1); p101 += __shfl_xor(p101, 1);
    p110 += __shfl_xor(p110, 1); p111 += __shfl_xor(p111, 1);

    // f32 edge MLP, channel-sliced: slice s covers c = s + 2*it; weights via LDS
    // broadcast (2 uniform b128 addresses/wave, disjoint banks).
    float m00 = 0.f, m01 = 0.f, m10 = 0.f, m11 = 0.f;
#pragma unroll 8
    for (int it = 0; it < 64; ++it) {
        float4 w = Wl[s + 2 * it];     // {a, b, beta, wd}
        float tt;
        tt = fmaf(p100, w.y, fmaf(p000, w.x, w.z)); tt = fmaxf(tt, 0.f); m00 = fmaf(tt, w.w, m00);
        tt = fmaf(p101, w.y, fmaf(p001, w.x, w.z)); tt = fmaxf(tt, 0.f); m01 = fmaf(tt, w.w, m01);
        tt = fmaf(p110, w.y, fmaf(p010, w.x, w.z)); tt = fmaxf(tt, 0.f); m10 = fmaf(tt, w.w, m10);
        tt = fmaf(p111, w.y, fmaf(p011, w.x, w.z)); tt = fmaxf(tt, 0.f); m11 = fmaf(tt, w.w, m11);
    }
    m00 += __shfl_xor(m00, 1); m01 += __shfl_xor(m01, 1);
    m10 += __shfl_xor(m10, 1); m11 += __shfl_xor(m11, 1);

    if (s == 0) {
        const double bd = (double)sm_b2[1] - (double)sm_b2[0];
        double i00 = bd + ((double)g0v.y - (double)g0v.x);
        double i01 = bd + ((double)g0v.w - (double)g0v.z);
        double i10 = bd + ((double)g1v.y - (double)g1v.x);
        double i11 = bd + ((double)g1v.w - (double)g1v.z);
        float f00 = m00 + (float)i00;
        float f01 = m01 + (float)i01;
        float f10 = m10 + (float)i10;
        float f11 = m11 + (float)i11;
        float A00 = f00 > 0.f ? 1.f : 0.f;
        float A01 = f01 > 0.f ? 1.f : 0.f;
        float A10 = f10 > 0.f ? 1.f : 0.f;
        float A11 = f11 > 0.f ? 1.f : 0.f;
        float fm = fminf(fminf(fabsf(f00), fabsf(f01)), fminf(fabsf(f10), fabsf(f11)));
        if (__builtin_expect(fm < THR, 0)) {
            // rare: exact f64 re-decide (bit-identical to the original f64 kernel)
            if (fabsf(f00) < THR) A00 = edge_exact_f64(Xc, wpack, b, gi0, gj0, i00) > 0.0 ? 1.f : 0.f;
            if (fabsf(f01) < THR) A01 = edge_exact_f64(Xc, wpack, b, gi0, gj1, i01) > 0.0 ? 1.f : 0.f;
            if (fabsf(f10) < THR) A10 = edge_exact_f64(Xc, wpack, b, gi1, gj0, i10) > 0.0 ? 1.f : 0.f;
            if (fabsf(f11) < THR) A11 = edge_exact_f64(Xc, wpack, b, gi1, gj1, i11) > 0.0 ? 1.f : 0.f;
        }
        As[r0][c0] = A00; As[r0][c1] = A01;
        As[r1][c0] = A10; As[r1][c1] = A11;
    }
    __syncthreads();

    if (s == 0) {
        float A00 = As[r0][c0], A01 = As[r0][c1];
        float A10 = As[r1][c0], A11 = As[r1][c1];
        if (ti != tj) {
            // direct tile (i<j guaranteed)
            *(float2*)&out[((size_t)b * NN + gi0) * NN + gj0] = make_float2(A00, A01);
            *(float2*)&out[((size_t)b * NN + gi1) * NN + gj0] = make_float2(A10, A11);
            // transposed tile: out[b, j0+jr, i0+ic] = As[ic][jr]
            float2 t0 = make_float2(As[c0][r0], As[c1][r0]);
            *(float2*)&out[((size_t)b * NN + j0 + r0) * NN + i0 + c0] = t0;
            float2 t1 = make_float2(As[c0][r1], As[c1][r1]);
            *(float2*)&out[((size_t)b * NN + j0 + r1) * NN + i0 + c0] = t1;
        } else {
            // diagonal tile: upper value mirrored, diag = 0
            float v00 = (r0 < c0) ? A00 : ((r0 > c0) ? As[c0][r0] : 0.0f);
            float v01 = (r0 < c1) ? A01 : ((r0 > c1) ? As[c1][r0] : 0.0f);
            float v10 = (r1 < c0) ? A10 : ((r1 > c0) ? As[c0][r1] : 0.0f);
            float v11 = (r1 < c1) ? A11 : ((r1 > c1) ? As[c1][r1] : 0.0f);
            *(float2*)&out[((size_t)b * NN + gi0) * NN + gj0] = make_float2(v00, v01);
            *(float2*)&out[((size_t)b * NN + gi1) * NN + gj0] = make_float2(v10, v11);
        }
    }
}

extern "C" void kernel_launch(void* const* d_in, const int* in_sizes, int n_in,
                              void* d_out, int out_size, void* d_ws, size_t ws_size,
                              hipStream_t stream) {
    const float* X      = (const float*)d_in[0];
    const float* ef_w1  = (const float*)d_in[1];
    const float* ef_b1  = (const float*)d_in[2];
    const float* ef_w2  = (const float*)d_in[3];
    const float* ef_b2  = (const float*)d_in[4];
    const float* gate   = (const float*)d_in[5];
    const float* sm_w1  = (const float*)d_in[6];
    const float* sm_b1  = (const float*)d_in[7];
    const float* sm_w2  = (const float*)d_in[8];
    const float* sm_b2  = (const float*)d_in[9];
    const float* gumbel = (const float*)d_in[10];
    float* out = (float*)d_out;

    double* Xc     = (double*)d_ws;                         // 2*2*768*64 doubles = 1.5 MiB
    double* wpack  = Xc + (size_t)BB * 2 * NN * 64;         // 512 doubles
    float4* wpackf = (float4*)(wpack + 4 * HH);             // 128 float4
    float*  Xcf    = (float*)(wpackf + HH);                 // 768 KiB f32 copy

    edgefeat_kernel<<<BB * NN / EROWS, 128, 0, stream>>>(
        X, ef_w1, ef_b1, ef_w2, ef_b2, gate, sm_w1, sm_b1, sm_w2, Xc, Xcf, wpack, wpackf);
    dim3 grid(NPAIR, BB);
    edge_decide_kernel<<<grid, 512, 0, stream>>>(Xc, Xcf, wpack, wpackf, sm_b2, gumbel, out);
}